// Round 9
// baseline (113.506 us; speedup 1.0000x reference)
//
#include <hip/hip_runtime.h>
#include <hip/hip_bf16.h>

// Problem constants (B,C,T,H,W = 2,64,8,48,48)
#define CC 64
#define TT 8
#define PP 2304        // 48*48
#define C2 32
#define BT 16          // B*T
#define NKT 36         // key/query tiles of 64
#define HKT 18         // NKT/2 (per key-group)
// log2(e)/sqrt(32): folds softmax scale AND exp->exp2 into theta pre-scale
#define SCALE2 0.25503486f

using h8 = __attribute__((ext_vector_type(8))) _Float16;  // 4 VGPRs
using h4 = __attribute__((ext_vector_type(4))) _Float16;  // 2 VGPRs
using f4 = __attribute__((ext_vector_type(4))) float;     // MFMA C/D frag

#if __has_builtin(__builtin_amdgcn_exp2f)
#define EXP2(v) __builtin_amdgcn_exp2f(v)
#else
#define EXP2(v) exp2f(v)
#endif

// XCD swizzle: grid (8, 72). lin%8 == blockIdx.x ~ XCD id; fixing x per bt
// pins all 36 consumer blocks of one bt to ONE XCD whose 4 MB L2 holds that
// bt's 1.16 MB record set; k_prep produces on the same XCD (L2-warm).
// Perf heuristic only.
#define SWIZ_BT(xcd, g) ((xcd) + 8 * ((g) & 1))
#define SWIZ_PT(g) ((g) >> 1)

// Workspace (_Float16):
//  thf[bt][pt][s16][lane][8]          theta B-frags (pre-scaled)   2.25 MB
//  rec[bt][kt] = 12 KB record:                                      7.08 MB
//     [0,4096) B:  phi A-frags [nt][lane][8h]
//     [4096,12288) B: x PV A-frag pairs [nt][ctp][lane][8h]

// ---------------------------------------------------------------------------
// k_prep: grid (8, 72), 256 thr. Unchanged from round 7.
// ---------------------------------------------------------------------------
__global__ __launch_bounds__(256) void k_prep(
    const float* __restrict__ x, const float* __restrict__ tw,
    const float* __restrict__ pw, _Float16* __restrict__ thf,
    _Float16* __restrict__ rec) {
  const int qt = SWIZ_PT(blockIdx.y), bt = SWIZ_BT(blockIdx.x, blockIdx.y);
  const int b = bt >> 3, t = bt & 7;
  const int tid = threadIdx.x;
  const int wv = tid >> 6, lane = tid & 63;
  const int quad = lane >> 4, l15 = lane & 15;

  __shared__ __align__(16) float x_s[64][68];         // [q_loc][c]
  __shared__ __align__(16) _Float16 th_s[4][16][32];  // per-wave [q16][c2]
  __shared__ __align__(16) _Float16 ph_s[4][16][32];

  const size_t xslice = ((size_t)b * CC * TT + t) * PP;
  const int qg0 = qt * 64;

  {
    const int qq = tid & 63;
    const int c0 = (tid >> 6) * 16;
#pragma unroll
    for (int i = 0; i < 16; i++) {
      int c = c0 + i;
      x_s[qq][c] = x[xslice + (size_t)c * (TT * PP) + qg0 + qq];
    }
  }
  __syncthreads();

  h8 bx[2];
#pragma unroll
  for (int ks = 0; ks < 2; ks++) {
    const float* row = &x_s[wv * 16 + l15][ks * 32 + quad * 8];
    float4 u0 = *reinterpret_cast<const float4*>(row);
    float4 u1 = *reinterpret_cast<const float4*>(row + 4);
    bx[ks][0] = (_Float16)u0.x; bx[ks][1] = (_Float16)u0.y;
    bx[ks][2] = (_Float16)u0.z; bx[ks][3] = (_Float16)u0.w;
    bx[ks][4] = (_Float16)u1.x; bx[ks][5] = (_Float16)u1.y;
    bx[ks][6] = (_Float16)u1.z; bx[ks][7] = (_Float16)u1.w;
  }

  const float* twt = tw + t * C2 * CC;
  const float* pwt = pw + t * C2 * CC;
  const f4 zero = {0.f, 0.f, 0.f, 0.f};
  f4 accT[2] = {zero, zero}, accP[2] = {zero, zero};
#pragma unroll
  for (int mt = 0; mt < 2; mt++)
#pragma unroll
    for (int ks = 0; ks < 2; ks++) {
      const float* wr = twt + (mt * 16 + l15) * CC + ks * 32 + quad * 8;
      const float* pr = pwt + (mt * 16 + l15) * CC + ks * 32 + quad * 8;
      float4 a0 = *reinterpret_cast<const float4*>(wr);
      float4 a1 = *reinterpret_cast<const float4*>(wr + 4);
      float4 p0 = *reinterpret_cast<const float4*>(pr);
      float4 p1 = *reinterpret_cast<const float4*>(pr + 4);
      h8 at = {(_Float16)a0.x, (_Float16)a0.y, (_Float16)a0.z, (_Float16)a0.w,
               (_Float16)a1.x, (_Float16)a1.y, (_Float16)a1.z, (_Float16)a1.w};
      h8 ap = {(_Float16)p0.x, (_Float16)p0.y, (_Float16)p0.z, (_Float16)p0.w,
               (_Float16)p1.x, (_Float16)p1.y, (_Float16)p1.z, (_Float16)p1.w};
      accT[mt] =
          __builtin_amdgcn_mfma_f32_16x16x32_f16(at, bx[ks], accT[mt], 0, 0, 0);
      accP[mt] =
          __builtin_amdgcn_mfma_f32_16x16x32_f16(ap, bx[ks], accP[mt], 0, 0, 0);
    }

#pragma unroll
  for (int mt = 0; mt < 2; mt++) {
    h4 tv, pv;
#pragma unroll
    for (int r = 0; r < 4; r++) {
      tv[r] = (_Float16)(accT[mt][r] * SCALE2);
      pv[r] = (_Float16)accP[mt][r];
    }
    *reinterpret_cast<h4*>(&th_s[wv][l15][mt * 16 + quad * 4]) = tv;
    *reinterpret_cast<h4*>(&ph_s[wv][l15][mt * 16 + quad * 4]) = pv;
  }
  // same-wave ds write->read ordering suffices

  h8 tfrag = *reinterpret_cast<const h8*>(&th_s[wv][l15][quad * 8]);
  *reinterpret_cast<h8*>(
      thf + (((size_t)(bt * NKT + qt) * 4 + wv) * 64 + lane) * 8) = tfrag;

  _Float16* rb = rec + (size_t)(bt * NKT + qt) * 6144;
  h8 pfrag = *reinterpret_cast<const h8*>(&ph_s[wv][l15][quad * 8]);
  *reinterpret_cast<h8*>(rb + wv * 512 + lane * 8) = pfrag;

#pragma unroll
  for (int ctp = 0; ctp < 2; ctp++) {
    h8 v;
#pragma unroll
    for (int j = 0; j < 4; j++) {
      v[j] = (_Float16)x_s[wv * 16 + quad * 4 + j][(2 * ctp) * 16 + l15];
      v[4 + j] = (_Float16)x_s[wv * 16 + quad * 4 + j][(2 * ctp + 1) * 16 + l15];
    }
    *reinterpret_cast<h8*>(rb + 2048 + (wv * 2 + ctp) * 512 + lane * 8) = v;
  }
}

// ---------------------------------------------------------------------------
// k_attn: grid (8, 72), 256 thr = 4 waves = 2 q-groups(32 p) x 2 key-groups.
// Each wave computes TWO p-subtiles from ONE aphi/xx LDS read stream:
// main-loop ds_read_b128 per block halves vs the 8-wave version (96->48
// per iter) at the same MFMA/exp count; 2 independent chains per wave.
// ---------------------------------------------------------------------------
__global__ __launch_bounds__(256, 3) void k_attn(
    const float* __restrict__ x, const _Float16* __restrict__ thf,
    const _Float16* __restrict__ rec, const float* __restrict__ ow,
    float* __restrict__ out) {
  const int pt = SWIZ_PT(blockIdx.y), bt = SWIZ_BT(blockIdx.x, blockIdx.y);
  const int b = bt >> 3, t = bt & 7;
  const int tid = threadIdx.x;
  const int wv = tid >> 6, lane = tid & 63;
  const int quad = lane >> 4, l15 = lane & 15;
  const int qg = wv & 1, kg = wv >> 1;

  // LDS: stage[2 buf][2 records][6144 halves] = 48 KB; epilogue reuses it.
  // Epilogue layout (after main-loop sync):
  //   exch : floats [0, 4352)        = bytes [0, 17408)   [4 psub][17][64]
  //   out_s: floats from byte 20480  = bytes [20480,37888) [64][68]
  // R8 BUG was out_s at 12288 — overlapped exch by 5 KB, corrupting the
  // q-group-1 exchange slabs. 20480 > 17408: disjoint.
  __shared__ __align__(16) char smem[49152];
  _Float16* stage = reinterpret_cast<_Float16*>(smem);
  float* exch = reinterpret_cast<float*>(smem);
  float* out_s = reinterpret_cast<float*>(smem + 20480);

  // theta B-frags for this wave's two p-subtiles: B[n=p][k=c2]
  h8 b_th[2];
#pragma unroll
  for (int ps = 0; ps < 2; ps++)
    b_th[ps] = *reinterpret_cast<const h8*>(
        thf + (((size_t)(bt * NKT + pt) * 4 + qg * 2 + ps) * 64 + lane) * 8);

  const _Float16* recb = rec + (size_t)bt * NKT * 6144;

  // staging: 24 x 1KB chunks per iter, 6 per wave
  int ch_tile[6], ch_off[6];
#pragma unroll
  for (int j = 0; j < 6; j++) {
    int m = wv * 6 + j;
    ch_tile[j] = m / 12;
    ch_off[j] = (m % 12) * 512 + lane * 8;  // halves
  }

  // prologue: stage iteration 0
  int4 v[6];
#pragma unroll
  for (int j = 0; j < 6; j++) {
    v[j] = *reinterpret_cast<const int4*>(
        recb + (size_t)(ch_tile[j] * HKT) * 6144 + ch_off[j]);
    *reinterpret_cast<int4*>(stage + ch_tile[j] * 6144 + ch_off[j]) = v[j];
  }

  const f4 zero = {0.f, 0.f, 0.f, 0.f};
  f4 O[2][4] = {{zero, zero, zero, zero}, {zero, zero, zero, zero}};
  float l_sum[2] = {0.f, 0.f};

  for (int i = 0; i < HKT; i++) {
    __syncthreads();  // buf[i&1] valid; prior reads of other buf done
    const _Float16* cur = stage + (i & 1) * 12288 + kg * 6144;

    // prefetch next iteration's chunks into registers
    if (i < HKT - 1) {
#pragma unroll
      for (int j = 0; j < 6; j++)
        v[j] = *reinterpret_cast<const int4*>(
            recb + (size_t)(ch_tile[j] * HKT + i + 1) * 6144 + ch_off[j]);
    }

    // S^T: 4 key-subtiles x 2 p-subtiles from ONE aphi read
    h8 aphi[4];
#pragma unroll
    for (int nt = 0; nt < 4; nt++)
      aphi[nt] = *reinterpret_cast<const h8*>(cur + nt * 512 + lane * 8);
    f4 s[4][2];
#pragma unroll
    for (int nt = 0; nt < 4; nt++)
#pragma unroll
      for (int ps = 0; ps < 2; ps++)
        s[nt][ps] = __builtin_amdgcn_mfma_f32_16x16x32_f16(aphi[nt], b_th[ps],
                                                           zero, 0, 0, 0);

    // w = exp2(s) in PV B-frag layout; PV from one xx read per (nt,ctp)
#pragma unroll
    for (int nt = 0; nt < 4; nt++) {
      h4 bw[2];
#pragma unroll
      for (int ps = 0; ps < 2; ps++)
#pragma unroll
        for (int r = 0; r < 4; r++) {
          float w = EXP2(s[nt][ps][r]);
          l_sum[ps] += w;
          bw[ps][r] = (_Float16)w;
        }
#pragma unroll
      for (int ctp = 0; ctp < 2; ctp++) {
        h8 xx = *reinterpret_cast<const h8*>(cur + 2048 + (nt * 2 + ctp) * 512 +
                                             lane * 8);
        h4 a0 = __builtin_shufflevector(xx, xx, 0, 1, 2, 3);
        h4 a1 = __builtin_shufflevector(xx, xx, 4, 5, 6, 7);
#pragma unroll
        for (int ps = 0; ps < 2; ps++) {
          O[ps][2 * ctp] = __builtin_amdgcn_mfma_f32_16x16x16f16(
              a0, bw[ps], O[ps][2 * ctp], 0, 0, 0);
          O[ps][2 * ctp + 1] = __builtin_amdgcn_mfma_f32_16x16x16f16(
              a1, bw[ps], O[ps][2 * ctp + 1], 0, 0, 0);
        }
      }
    }

    // commit prefetched chunks to the other buffer
    if (i < HKT - 1) {
#pragma unroll
      for (int j = 0; j < 6; j++)
        *reinterpret_cast<int4*>(stage + ((i + 1) & 1) * 12288 +
                                 ch_tile[j] * 6144 + ch_off[j]) = v[j];
    }
  }

  // l: combine quad groups (lane's p fixed per psub)
#pragma unroll
  for (int ps = 0; ps < 2; ps++) {
    l_sum[ps] += __shfl_xor(l_sum[ps], 16);
    l_sum[ps] += __shfl_xor(l_sum[ps], 32);
  }

  __syncthreads();  // main loop done; LDS reusable

  // key-group combine via LDS exchange
  if (kg == 1) {
#pragma unroll
    for (int ps = 0; ps < 2; ps++) {
#pragma unroll
      for (int k = 0; k < 16; k++)
        exch[((qg * 2 + ps) * 17 + k) * 64 + lane] = O[ps][k >> 2][k & 3];
      exch[((qg * 2 + ps) * 17 + 16) * 64 + lane] = l_sum[ps];
    }
  }
  __syncthreads();

  if (kg == 0) {
#pragma unroll
    for (int ps = 0; ps < 2; ps++) {
#pragma unroll
      for (int k = 0; k < 16; k++)
        O[ps][k >> 2][k & 3] += exch[((qg * 2 + ps) * 17 + k) * 64 + lane];
      const float inv =
          1.f / (l_sum[ps] + exch[((qg * 2 + ps) * 17 + 16) * 64 + lane]);

      h4 bf[4];
#pragma unroll
      for (int ct = 0; ct < 4; ct++)
#pragma unroll
        for (int r = 0; r < 4; r++) bf[ct][r] = (_Float16)(O[ps][ct][r] * inv);

      f4 D3[4] = {zero, zero, zero, zero};
#pragma unroll
      for (int mt = 0; mt < 4; mt++)
#pragma unroll
        for (int ct = 0; ct < 4; ct++) {
          const float* wrow =
              ow + (size_t)(mt * 16 + l15) * CC + ct * 16 + quad * 4;
          float4 u = *reinterpret_cast<const float4*>(wrow);
          h4 aw = {(_Float16)u.x, (_Float16)u.y, (_Float16)u.z, (_Float16)u.w};
          D3[mt] =
              __builtin_amdgcn_mfma_f32_16x16x16f16(aw, bf[ct], D3[mt], 0, 0, 0);
        }

#pragma unroll
      for (int mt = 0; mt < 4; mt++)
#pragma unroll
        for (int r = 0; r < 4; r++)
          out_s[(mt * 16 + quad * 4 + r) * 68 + (qg * 2 + ps) * 16 + l15] =
              D3[mt][r];
    }
  }
  __syncthreads();

  // coalesced stores with fp32 residual: 256 thr x 16 floats
  const int co = tid >> 2;
  const int psub = (tid & 3) * 16;
  const size_t gbase = ((size_t)(b * CC + co) * TT + t) * PP + pt * 64 + psub;
#pragma unroll
  for (int jj = 0; jj < 4; jj++) {
    float4 vo =
        *reinterpret_cast<const float4*>(&out_s[co * 68 + psub + jj * 4]);
    float4 xr = *reinterpret_cast<const float4*>(&x[gbase + jj * 4]);
    vo.x += xr.x; vo.y += xr.y; vo.z += xr.z; vo.w += xr.w;
    *reinterpret_cast<float4*>(&out[gbase + jj * 4]) = vo;
  }
}

extern "C" void kernel_launch(void* const* d_in, const int* in_sizes, int n_in,
                              void* d_out, int out_size, void* d_ws,
                              size_t ws_size, hipStream_t stream) {
  (void)in_sizes; (void)n_in; (void)out_size; (void)ws_size;
  const float* x = (const float*)d_in[0];
  const float* tw = (const float*)d_in[1];
  const float* pw = (const float*)d_in[2];
  const float* ow = (const float*)d_in[3];
  float* out = (float*)d_out;

  _Float16* thf = (_Float16*)d_ws;                      // 2.25 MB
  _Float16* rec = thf + (size_t)BT * NKT * 4 * 64 * 8;  // 7.08 MB

  k_prep<<<dim3(8, 72), 256, 0, stream>>>(x, tw, pw, thf, rec);
  k_attn<<<dim3(8, 72), 256, 0, stream>>>(x, thf, rec, ow, out);
}

// Round 11
// 110.301 us; speedup vs baseline: 1.0291x; 1.0291x over previous
//
#include <hip/hip_runtime.h>
#include <hip/hip_bf16.h>

// Problem constants (B,C,T,H,W = 2,64,8,48,48)
#define CC 64
#define TT 8
#define PP 2304        // 48*48
#define C2 32
#define BT 16          // B*T
#define NKT 36         // key/query tiles of 64
#define HKT 18         // NKT/2 (per key-group)
// log2(e)/sqrt(32): folds softmax scale AND exp->exp2 into theta pre-scale
#define SCALE2 0.25503486f

using h8 = __attribute__((ext_vector_type(8))) _Float16;  // 4 VGPRs
using h4 = __attribute__((ext_vector_type(4))) _Float16;  // 2 VGPRs
using f4 = __attribute__((ext_vector_type(4))) float;     // MFMA C/D frag

#if __has_builtin(__builtin_amdgcn_exp2f)
#define EXP2(v) __builtin_amdgcn_exp2f(v)
#else
#define EXP2(v) exp2f(v)
#endif

// XCD swizzle: grid (8, 72). lin%8 == blockIdx.x ~ XCD id; fixing x per bt
// pins all 36 consumer blocks of one bt to ONE XCD whose 4 MB L2 holds that
// bt's 1.16 MB record set; k_prep produces on the same XCD (L2-warm).
// Verified: FETCH_SIZE 33.5 -> 9.3 MB (r9). Perf heuristic only.
#define SWIZ_BT(xcd, g) ((xcd) + 8 * ((g) & 1))
#define SWIZ_PT(g) ((g) >> 1)

// Workspace (_Float16):
//  thf[bt][pt][s16][lane][8]          theta B-frags (pre-scaled)   2.25 MB
//  rec[bt][kt] = 12 KB record (6144 halves):                        7.08 MB
//     [0,4096) B:  phi A-frags [nt][lane][8h]
//     [4096,12288) B: x PV A-frag pairs [nt][ctp][lane][8h]
// All reads are base + lane*16B: fully coalesced b128, L2-resident (swizzle).

// ---------------------------------------------------------------------------
// k_prep: grid (8, 72), 256 thr. Unchanged from round 7/9 (verified).
// ---------------------------------------------------------------------------
__global__ __launch_bounds__(256) void k_prep(
    const float* __restrict__ x, const float* __restrict__ tw,
    const float* __restrict__ pw, _Float16* __restrict__ thf,
    _Float16* __restrict__ rec) {
  const int qt = SWIZ_PT(blockIdx.y), bt = SWIZ_BT(blockIdx.x, blockIdx.y);
  const int b = bt >> 3, t = bt & 7;
  const int tid = threadIdx.x;
  const int wv = tid >> 6, lane = tid & 63;
  const int quad = lane >> 4, l15 = lane & 15;

  __shared__ __align__(16) float x_s[64][68];         // [q_loc][c]
  __shared__ __align__(16) _Float16 th_s[4][16][32];  // per-wave [q16][c2]
  __shared__ __align__(16) _Float16 ph_s[4][16][32];

  const size_t xslice = ((size_t)b * CC * TT + t) * PP;
  const int qg0 = qt * 64;

  {
    const int qq = tid & 63;
    const int c0 = (tid >> 6) * 16;
#pragma unroll
    for (int i = 0; i < 16; i++) {
      int c = c0 + i;
      x_s[qq][c] = x[xslice + (size_t)c * (TT * PP) + qg0 + qq];
    }
  }
  __syncthreads();

  h8 bx[2];
#pragma unroll
  for (int ks = 0; ks < 2; ks++) {
    const float* row = &x_s[wv * 16 + l15][ks * 32 + quad * 8];
    float4 u0 = *reinterpret_cast<const float4*>(row);
    float4 u1 = *reinterpret_cast<const float4*>(row + 4);
    bx[ks][0] = (_Float16)u0.x; bx[ks][1] = (_Float16)u0.y;
    bx[ks][2] = (_Float16)u0.z; bx[ks][3] = (_Float16)u0.w;
    bx[ks][4] = (_Float16)u1.x; bx[ks][5] = (_Float16)u1.y;
    bx[ks][6] = (_Float16)u1.z; bx[ks][7] = (_Float16)u1.w;
  }

  const float* twt = tw + t * C2 * CC;
  const float* pwt = pw + t * C2 * CC;
  const f4 zero = {0.f, 0.f, 0.f, 0.f};
  f4 accT[2] = {zero, zero}, accP[2] = {zero, zero};
#pragma unroll
  for (int mt = 0; mt < 2; mt++)
#pragma unroll
    for (int ks = 0; ks < 2; ks++) {
      const float* wr = twt + (mt * 16 + l15) * CC + ks * 32 + quad * 8;
      const float* pr = pwt + (mt * 16 + l15) * CC + ks * 32 + quad * 8;
      float4 a0 = *reinterpret_cast<const float4*>(wr);
      float4 a1 = *reinterpret_cast<const float4*>(wr + 4);
      float4 p0 = *reinterpret_cast<const float4*>(pr);
      float4 p1 = *reinterpret_cast<const float4*>(pr + 4);
      h8 at = {(_Float16)a0.x, (_Float16)a0.y, (_Float16)a0.z, (_Float16)a0.w,
               (_Float16)a1.x, (_Float16)a1.y, (_Float16)a1.z, (_Float16)a1.w};
      h8 ap = {(_Float16)p0.x, (_Float16)p0.y, (_Float16)p0.z, (_Float16)p0.w,
               (_Float16)p1.x, (_Float16)p1.y, (_Float16)p1.z, (_Float16)p1.w};
      accT[mt] =
          __builtin_amdgcn_mfma_f32_16x16x32_f16(at, bx[ks], accT[mt], 0, 0, 0);
      accP[mt] =
          __builtin_amdgcn_mfma_f32_16x16x32_f16(ap, bx[ks], accP[mt], 0, 0, 0);
    }

#pragma unroll
  for (int mt = 0; mt < 2; mt++) {
    h4 tv, pv;
#pragma unroll
    for (int r = 0; r < 4; r++) {
      tv[r] = (_Float16)(accT[mt][r] * SCALE2);
      pv[r] = (_Float16)accP[mt][r];
    }
    *reinterpret_cast<h4*>(&th_s[wv][l15][mt * 16 + quad * 4]) = tv;
    *reinterpret_cast<h4*>(&ph_s[wv][l15][mt * 16 + quad * 4]) = pv;
  }
  // same-wave ds write->read ordering suffices

  h8 tfrag = *reinterpret_cast<const h8*>(&th_s[wv][l15][quad * 8]);
  *reinterpret_cast<h8*>(
      thf + (((size_t)(bt * NKT + qt) * 4 + wv) * 64 + lane) * 8) = tfrag;

  _Float16* rb = rec + (size_t)(bt * NKT + qt) * 6144;
  h8 pfrag = *reinterpret_cast<const h8*>(&ph_s[wv][l15][quad * 8]);
  *reinterpret_cast<h8*>(rb + wv * 512 + lane * 8) = pfrag;

#pragma unroll
  for (int ctp = 0; ctp < 2; ctp++) {
    h8 v;
#pragma unroll
    for (int j = 0; j < 4; j++) {
      v[j] = (_Float16)x_s[wv * 16 + quad * 4 + j][(2 * ctp) * 16 + l15];
      v[4 + j] = (_Float16)x_s[wv * 16 + quad * 4 + j][(2 * ctp + 1) * 16 + l15];
    }
    *reinterpret_cast<h8*>(rb + 2048 + (wv * 2 + ctp) * 512 + lane * 8) = v;
  }
}

// ---------------------------------------------------------------------------
// k_attn: grid (8, 72), 256 thr = 4 waves = 2 q-groups(32 p) x 2 key-groups.
// r11: NO LDS staging, NO main-loop barriers. Each wave streams its
// key-group's 18 records directly from global (L2-resident via swizzle)
// with one-record register prefetch (12 x int4 in flight). Math layouts
// identical to verified r9. LDS only holds the two small disjoint
// epilogue arrays (no aliasing).
// ---------------------------------------------------------------------------
__global__ __launch_bounds__(256, 3) void k_attn(
    const float* __restrict__ x, const _Float16* __restrict__ thf,
    const _Float16* __restrict__ rec, const float* __restrict__ ow,
    float* __restrict__ out) {
  const int pt = SWIZ_PT(blockIdx.y), bt = SWIZ_BT(blockIdx.x, blockIdx.y);
  const int b = bt >> 3, t = bt & 7;
  const int tid = threadIdx.x;
  const int wv = tid >> 6, lane = tid & 63;
  const int quad = lane >> 4, l15 = lane & 15;
  const int qg = wv & 1, kg = wv >> 1;

  __shared__ __align__(16) float exch[4 * 17 * 64];   // 17408 B
  __shared__ __align__(16) float out_s[64 * 68];      // 17408 B (disjoint)

  // theta B-frags for this wave's two p-subtiles: B[n=p][k=c2]
  h8 b_th[2];
#pragma unroll
  for (int ps = 0; ps < 2; ps++)
    b_th[ps] = *reinterpret_cast<const h8*>(
        thf + (((size_t)(bt * NKT + pt) * 4 + qg * 2 + ps) * 64 + lane) * 8);

  // this wave's record stream: records kg*18 .. kg*18+17
  const _Float16* mybase =
      rec + ((size_t)bt * NKT + (size_t)kg * HKT) * 6144 + lane * 8;

  // prologue: load record 0 into cur
  int4 cur[12], nxt[12];
#pragma unroll
  for (int j = 0; j < 12; j++)
    cur[j] = *reinterpret_cast<const int4*>(mybase + j * 512);

  const f4 zero = {0.f, 0.f, 0.f, 0.f};
  f4 O[2][4] = {{zero, zero, zero, zero}, {zero, zero, zero, zero}};
  float l_sum[2] = {0.f, 0.f};

  for (int i = 0; i < HKT; i++) {
    // issue next record's loads first (independent; fly during compute)
    if (i < HKT - 1) {
      const _Float16* nb = mybase + (size_t)(i + 1) * 6144;
#pragma unroll
      for (int j = 0; j < 12; j++)
        nxt[j] = *reinterpret_cast<const int4*>(nb + j * 512);
    }

    // S^T: 4 key-subtiles x 2 p-subtiles
    f4 s[4][2];
#pragma unroll
    for (int nt = 0; nt < 4; nt++) {
      h8 aphi = *reinterpret_cast<const h8*>(&cur[nt]);
#pragma unroll
      for (int ps = 0; ps < 2; ps++)
        s[nt][ps] = __builtin_amdgcn_mfma_f32_16x16x32_f16(aphi, b_th[ps],
                                                           zero, 0, 0, 0);
    }

    // w = exp2(s) in PV B-frag layout; PV from register xx frags
#pragma unroll
    for (int nt = 0; nt < 4; nt++) {
      h4 bw[2];
#pragma unroll
      for (int ps = 0; ps < 2; ps++)
#pragma unroll
        for (int r = 0; r < 4; r++) {
          float w = EXP2(s[nt][ps][r]);
          l_sum[ps] += w;
          bw[ps][r] = (_Float16)w;
        }
#pragma unroll
      for (int ctp = 0; ctp < 2; ctp++) {
        h8 xx = *reinterpret_cast<const h8*>(&cur[4 + nt * 2 + ctp]);
        h4 a0 = __builtin_shufflevector(xx, xx, 0, 1, 2, 3);
        h4 a1 = __builtin_shufflevector(xx, xx, 4, 5, 6, 7);
#pragma unroll
        for (int ps = 0; ps < 2; ps++) {
          O[ps][2 * ctp] = __builtin_amdgcn_mfma_f32_16x16x16f16(
              a0, bw[ps], O[ps][2 * ctp], 0, 0, 0);
          O[ps][2 * ctp + 1] = __builtin_amdgcn_mfma_f32_16x16x16f16(
              a1, bw[ps], O[ps][2 * ctp + 1], 0, 0, 0);
        }
      }
    }

    // rotate prefetch
    if (i < HKT - 1) {
#pragma unroll
      for (int j = 0; j < 12; j++) cur[j] = nxt[j];
    }
  }

  // l: combine quad groups (lane's p fixed per psub)
#pragma unroll
  for (int ps = 0; ps < 2; ps++) {
    l_sum[ps] += __shfl_xor(l_sum[ps], 16);
    l_sum[ps] += __shfl_xor(l_sum[ps], 32);
  }

  // key-group combine via LDS exchange (identical to verified r9)
  if (kg == 1) {
#pragma unroll
    for (int ps = 0; ps < 2; ps++) {
#pragma unroll
      for (int k = 0; k < 16; k++)
        exch[((qg * 2 + ps) * 17 + k) * 64 + lane] = O[ps][k >> 2][k & 3];
      exch[((qg * 2 + ps) * 17 + 16) * 64 + lane] = l_sum[ps];
    }
  }
  __syncthreads();

  if (kg == 0) {
#pragma unroll
    for (int ps = 0; ps < 2; ps++) {
#pragma unroll
      for (int k = 0; k < 16; k++)
        O[ps][k >> 2][k & 3] += exch[((qg * 2 + ps) * 17 + k) * 64 + lane];
      const float inv =
          1.f / (l_sum[ps] + exch[((qg * 2 + ps) * 17 + 16) * 64 + lane]);

      h4 bf[4];
#pragma unroll
      for (int ct = 0; ct < 4; ct++)
#pragma unroll
        for (int r = 0; r < 4; r++) bf[ct][r] = (_Float16)(O[ps][ct][r] * inv);

      f4 D3[4] = {zero, zero, zero, zero};
#pragma unroll
      for (int mt = 0; mt < 4; mt++)
#pragma unroll
        for (int ct = 0; ct < 4; ct++) {
          const float* wrow =
              ow + (size_t)(mt * 16 + l15) * CC + ct * 16 + quad * 4;
          float4 u = *reinterpret_cast<const float4*>(wrow);
          h4 aw = {(_Float16)u.x, (_Float16)u.y, (_Float16)u.z, (_Float16)u.w};
          D3[mt] =
              __builtin_amdgcn_mfma_f32_16x16x16f16(aw, bf[ct], D3[mt], 0, 0, 0);
        }

#pragma unroll
      for (int mt = 0; mt < 4; mt++)
#pragma unroll
        for (int r = 0; r < 4; r++)
          out_s[(mt * 16 + quad * 4 + r) * 68 + (qg * 2 + ps) * 16 + l15] =
              D3[mt][r];
    }
  }
  __syncthreads();

  // coalesced stores with fp32 residual: 256 thr x 16 floats
  const int co = tid >> 2;
  const int psub = (tid & 3) * 16;
  const size_t gbase = ((size_t)(b * CC + co) * TT + t) * PP + pt * 64 + psub;
#pragma unroll
  for (int jj = 0; jj < 4; jj++) {
    float4 vo =
        *reinterpret_cast<const float4*>(&out_s[co * 68 + psub + jj * 4]);
    float4 xr = *reinterpret_cast<const float4*>(&x[gbase + jj * 4]);
    vo.x += xr.x; vo.y += xr.y; vo.z += xr.z; vo.w += xr.w;
    *reinterpret_cast<float4*>(&out[gbase + jj * 4]) = vo;
  }
}

extern "C" void kernel_launch(void* const* d_in, const int* in_sizes, int n_in,
                              void* d_out, int out_size, void* d_ws,
                              size_t ws_size, hipStream_t stream) {
  (void)in_sizes; (void)n_in; (void)out_size; (void)ws_size;
  const float* x = (const float*)d_in[0];
  const float* tw = (const float*)d_in[1];
  const float* pw = (const float*)d_in[2];
  const float* ow = (const float*)d_in[3];
  float* out = (float*)d_out;

  _Float16* thf = (_Float16*)d_ws;                      // 2.25 MB
  _Float16* rec = thf + (size_t)BT * NKT * 4 * 64 * 8;  // 7.08 MB

  k_prep<<<dim3(8, 72), 256, 0, stream>>>(x, tw, pw, thf, rec);
  k_attn<<<dim3(8, 72), 256, 0, stream>>>(x, thf, rec, ow, out);
}